// Round 9
// baseline (112.158 us; speedup 1.0000x reference)
//
#include <hip/hip_runtime.h>

// Problem constants (from reference)
#define BB     32
#define C_IN   64
#define HH     64
#define WW     64
#define C_OUT  128
#define CONN   4     // 1 << TREE_DEPTH
// PADDING=2 -> pad_l = pad_r = 1, "edge" mode -> clamp coords to [0, 63]

// DIAGNOSTIC ROUND: round-8 kernel (XCD swizzle + NT stores, proven best at
// ~24.6 us) but executing the ENTIRE pass TWICE inside one dispatch. The
// per-rep asm-opaque pointers stop the compiler from CSE-ing pass-2 loads or
// dead-store-eliminating pass-1 stores, so the dispatch is ~2x the true
// kernel time (~49 us) -- ABOVE the 42-43 us harness poison-fills, making it
// visible to rocprof top-5 with full counters. Output is identical (pass 2
// overwrites with the same values); same work every call (graph-safe).
__global__ __launch_bounds__(256) void lp_conv_bt_kernel(
    const float* __restrict__ x,       // (B, C_IN, H, W)
    const float* __restrict__ weights, // (C_OUT, CONN)
    const float* __restrict__ bias,    // (C_OUT)
    const int*   __restrict__ conn,    // (C_OUT, CONN)
    float*       __restrict__ out)     // (B, C_OUT, H, W)
{
    const int bid = blockIdx.x;        // 8192 = 8 xcd * 4 b * 128 o * 2 half
    const int xcd = bid & 7;
    const int n   = bid >> 3;          // [0,1024), sequential per XCD
    const int b   = (xcd << 2) | (n >> 8);
    const int o   = (n >> 1) & (C_OUT - 1);
    const int ihalf = n & 1;

    const int tid  = threadIdx.x;
    const int lane = tid & 63;
    int i0 = ihalf * 32 + (tid >> 6) * 8;
    i0 = __builtin_amdgcn_readfirstlane(i0);   // wave-uniform -> SALU addressing

    for (int rep = 0; rep < 2; ++rep) {
        // Opaque per-rep pointers: compiler cannot prove they equal the
        // originals, so pass-2 loads reload and pass-1 stores survive DSE.
        const float* xr = x;
        float*       outr = out;
        asm volatile("" : "+s"(xr));
        asm volatile("" : "+s"(outr));

        float acc[8];
#pragma unroll
        for (int i = 0; i < 8; ++i) acc[i] = 0.f;

#pragma unroll
        for (int k = 0; k < CONN; ++k) {
            const int   ci = conn[o * CONN + k];   // uniform -> s_load
            const float wk = weights[o * CONN + k];
            int c   = ci / 9;
            int rem = ci - c * 9;
            int di  = rem / 3;
            int dj  = rem - di * 3;

            int col = lane + dj - 1;               // per-lane column, clamped
            col = min(max(col, 0), WW - 1);

            const float* base = xr + (((size_t)b * C_IN + c) << 12);

#pragma unroll
            for (int i = 0; i < 8; ++i) {
                int hh = i0 + i + di - 1;          // wave-uniform row
                hh = min(max(hh, 0), HH - 1);
                float v = base[(hh << 6) + col];
                acc[i] = fmaxf(acc[i], fabsf(wk - v));
            }
        }

        const float bo = bias[o];
        float* po = outr + (((size_t)(b * C_OUT + o) * HH + i0) << 6) + lane;
#pragma unroll
        for (int i = 0; i < 8; ++i)
            __builtin_nontemporal_store(acc[i] + bo, po + (i << 6));
    }
}

extern "C" void kernel_launch(void* const* d_in, const int* in_sizes, int n_in,
                              void* d_out, int out_size, void* d_ws, size_t ws_size,
                              hipStream_t stream) {
    const float* x       = (const float*)d_in[0];
    const float* weights = (const float*)d_in[1];
    const float* bias    = (const float*)d_in[2];
    const int*   conn    = (const int*)d_in[3];
    float*       out     = (float*)d_out;

    int grid = BB * C_OUT * 2;   // 8192 blocks of 256 threads
    lp_conv_bt_kernel<<<grid, 256, 0, stream>>>(x, weights, bias, conn, out);
}

// Round 13
// 108.059 us; speedup vs baseline: 1.0379x; 1.0379x over previous
//
#include <hip/hip_runtime.h>

// Problem constants (from reference)
#define BB     32
#define C_IN   64
#define HH     64
#define WW     64
#define C_OUT  128
#define CONN   4     // 1 << TREE_DEPTH
// PADDING=2 -> pad_l = pad_r = 1, "edge" mode -> clamp coords to [0, 63]

// Native clang vector type: __builtin_nontemporal_store requires a vector of
// scalars, not HIP's float4 class.
typedef float f32x4 __attribute__((ext_vector_type(4)));

// Round-10 structure: float4 (16 B/lane) loads + shfl column shift.
//  Diagnosis from round-9 2-pass profile: VALUBusy 25%, HBM 32%, occ 61%,
//  VGPR 20 -> latency/VMEM-issue bound with 4 B/lane payloads. Fix: quarter
//  the VMEM instruction count by loading 16 B per lane.
//  - block = one (b,o) image, 256 thr = 4 waves; wave w owns rows 16w..16w+15
//  - lane: r = lane>>4 (row-within-4), q = lane&15 (col quarter, j0 = 4q)
//  - per (k, s): row = i0 + 4s + r + di - 1 (clamped), ONE aligned f32x4
//    load of cols [4q, 4q+3]; input col j+dj-1 needs 4q-1 (left neighbor's
//    elem 3 via __shfl) or 4q+4 (right neighbor's elem 0) -- dj is uniform
//    per k so it's a uniform branch; q==0/15 lanes clamp to own edge elem.
//  - XCD swizzle (b slowest per XCD, x stays L2-resident) + NT stores
//    (output stream must not thrash L2) both retained from rounds 7-8.
__global__ __launch_bounds__(256) void lp_conv_bt_kernel(
    const float* __restrict__ x,       // (B, C_IN, H, W)
    const float* __restrict__ weights, // (C_OUT, CONN)
    const float* __restrict__ bias,    // (C_OUT)
    const int*   __restrict__ conn,    // (C_OUT, CONN)
    float*       __restrict__ out)     // (B, C_OUT, H, W)
{
    const int bid = blockIdx.x;        // 4096 = 8 xcd * 4 b * 128 o
    const int xcd = bid & 7;
    const int n   = bid >> 3;          // [0,512), sequential per XCD
    const int b   = (xcd << 2) | (n >> 7);   // b slowest within an XCD
    const int o   = n & (C_OUT - 1);

    const int tid  = threadIdx.x;
    const int lane = tid & 63;
    const int q    = lane & 15;        // col quarter: j0 = 4q
    const int r    = lane >> 4;        // row within group of 4
    int i0 = (tid >> 6) << 4;          // wave base row
    i0 = __builtin_amdgcn_readfirstlane(i0);

    f32x4 acc[4];
#pragma unroll
    for (int s = 0; s < 4; ++s) acc[s] = (f32x4)(0.f);

#pragma unroll
    for (int k = 0; k < CONN; ++k) {
        const int   ci = conn[o * CONN + k];   // uniform -> s_load
        const float wk = weights[o * CONN + k];
        int c   = ci / 9;
        int rem = ci - c * 9;
        int di  = rem / 3;
        int dj  = rem - di * 3;

        const float* base = x + (((size_t)b * C_IN + c) << 12);  // channel base

        // batch 4 independent 16B loads (rows i0+4s+r, shifted by di-1)
        f32x4 v[4];
#pragma unroll
        for (int s = 0; s < 4; ++s) {
            int row = i0 + 4 * s + r + di - 1;
            row = min(max(row, 0), HH - 1);
            v[s] = *reinterpret_cast<const f32x4*>(base + (row << 6) + (q << 2));
        }

        if (dj == 0) {          // need cols 4q-1 .. 4q+2
#pragma unroll
            for (int s = 0; s < 4; ++s) {
                float pw   = __shfl(v[s][3], lane - 1);
                float left = (q == 0) ? v[s][0] : pw;   // col -1 -> clamp to 0
                acc[s][0] = fmaxf(acc[s][0], fabsf(wk - left));
                acc[s][1] = fmaxf(acc[s][1], fabsf(wk - v[s][0]));
                acc[s][2] = fmaxf(acc[s][2], fabsf(wk - v[s][1]));
                acc[s][3] = fmaxf(acc[s][3], fabsf(wk - v[s][2]));
            }
        } else if (dj == 1) {   // cols 4q .. 4q+3
#pragma unroll
            for (int s = 0; s < 4; ++s) {
                acc[s][0] = fmaxf(acc[s][0], fabsf(wk - v[s][0]));
                acc[s][1] = fmaxf(acc[s][1], fabsf(wk - v[s][1]));
                acc[s][2] = fmaxf(acc[s][2], fabsf(wk - v[s][2]));
                acc[s][3] = fmaxf(acc[s][3], fabsf(wk - v[s][3]));
            }
        } else {                // dj == 2: cols 4q+1 .. 4q+4
#pragma unroll
            for (int s = 0; s < 4; ++s) {
                float nx    = __shfl(v[s][0], lane + 1);
                float right = (q == 15) ? v[s][3] : nx; // col 64 -> clamp to 63
                acc[s][0] = fmaxf(acc[s][0], fabsf(wk - v[s][1]));
                acc[s][1] = fmaxf(acc[s][1], fabsf(wk - v[s][2]));
                acc[s][2] = fmaxf(acc[s][2], fabsf(wk - v[s][3]));
                acc[s][3] = fmaxf(acc[s][3], fabsf(wk - right));
            }
        }
    }

    const float bo = bias[o];
    float* po = out + (((size_t)(b * C_OUT + o) * HH) << 6);
#pragma unroll
    for (int s = 0; s < 4; ++s) {
        int row = i0 + 4 * s + r;
        f32x4 rv = acc[s] + bo;
        __builtin_nontemporal_store(rv,
            reinterpret_cast<f32x4*>(po + (row << 6) + (q << 2)));
    }
}

extern "C" void kernel_launch(void* const* d_in, const int* in_sizes, int n_in,
                              void* d_out, int out_size, void* d_ws, size_t ws_size,
                              hipStream_t stream) {
    const float* x       = (const float*)d_in[0];
    const float* weights = (const float*)d_in[1];
    const float* bias    = (const float*)d_in[2];
    const int*   conn    = (const int*)d_in[3];
    float*       out     = (float*)d_out;

    int grid = BB * C_OUT;   // 4096 blocks of 256 threads
    lp_conv_bt_kernel<<<grid, 256, 0, stream>>>(x, weights, bias, conn, out);
}

// Round 16
// 103.913 us; speedup vs baseline: 1.0793x; 1.0399x over previous
//
#include <hip/hip_runtime.h>

// Problem constants (from reference)
#define BB     32
#define C_IN   64
#define HH     64
#define WW     64
#define C_OUT  128
#define CONN   4     // 1 << TREE_DEPTH
// PADDING=2 -> pad_l = pad_r = 1, "edge" mode -> clamp coords to [0, 63]

// Round-14: round-8 frame (proven best: lane=j coalesced scalar loads, 8
// rows/thread, XCD swizzle with b slowest per XCD, NT stores) + FULL LOAD
// HOIST: all 32 x-loads (4 conns x 8 rows) are issued before any consume.
//  Diagnosis: round-9 profile showed VALUBusy 25%, HBM 32%, occ 61%, and
//  VGPR_Count=20 -> the compiler kept only one 8-load batch in flight; each
//  wave stalls 4x per pass on L2 latency (~200-400 cy). Round-13's float4
//  variant disproved the VMEM-instruction-count theory (line count is
//  invariant; it regressed). This round raises per-wave MLP 4x instead.
//  __launch_bounds__(256,6): >=6 waves/SIMD (~85 VGPR cap) so the hoist
//  survives without killing occupancy.
__global__ __launch_bounds__(256, 6) void lp_conv_bt_kernel(
    const float* __restrict__ x,       // (B, C_IN, H, W)
    const float* __restrict__ weights, // (C_OUT, CONN)
    const float* __restrict__ bias,    // (C_OUT)
    const int*   __restrict__ conn,    // (C_OUT, CONN)
    float*       __restrict__ out)     // (B, C_OUT, H, W)
{
    const int bid = blockIdx.x;        // 8192 = 8 xcd * 4 b * 128 o * 2 half
    const int xcd = bid & 7;
    const int n   = bid >> 3;          // [0,1024), sequential per XCD
    const int b   = (xcd << 2) | (n >> 8);   // b slowest within an XCD
    const int o   = (n >> 1) & (C_OUT - 1);
    const int ihalf = n & 1;

    const int tid  = threadIdx.x;
    const int lane = tid & 63;
    int i0 = ihalf * 32 + (tid >> 6) * 8;
    i0 = __builtin_amdgcn_readfirstlane(i0);   // wave-uniform -> SALU rows

    // Decode all connections up front (uniform scalar work + one clamp/lane)
    int   cc[CONN], dd[CONN], colv[CONN];
    float wk[CONN];
#pragma unroll
    for (int k = 0; k < CONN; ++k) {
        const int ci = conn[o * CONN + k];     // uniform -> s_load
        wk[k] = weights[o * CONN + k];
        int c   = ci / 9;
        int rem = ci - c * 9;
        int di  = rem / 3;
        int dj  = rem - di * 3;
        cc[k] = c;
        dd[k] = di;
        int col = lane + dj - 1;               // per-lane column, clamped
        colv[k] = min(max(col, 0), WW - 1);
    }

    // Issue ALL 32 independent loads before any consume -> 32 in flight/wave
    float v[CONN][8];
#pragma unroll
    for (int k = 0; k < CONN; ++k) {
        const float* base = x + (((size_t)b * C_IN + cc[k]) << 12);
#pragma unroll
        for (int i = 0; i < 8; ++i) {
            int hh = i0 + i + dd[k] - 1;       // wave-uniform row
            hh = min(max(hh, 0), HH - 1);
            v[k][i] = base[(hh << 6) + colv[k]];
        }
    }

    // Consume in issue order (compiler emits incremental vmcnt waits)
    float acc[8];
#pragma unroll
    for (int i = 0; i < 8; ++i) acc[i] = 0.f;
#pragma unroll
    for (int k = 0; k < CONN; ++k)
#pragma unroll
        for (int i = 0; i < 8; ++i)
            acc[i] = fmaxf(acc[i], fabsf(wk[k] - v[k][i]));

    const float bo = bias[o];
    float* po = out + (((size_t)(b * C_OUT + o) * HH + i0) << 6) + lane;
#pragma unroll
    for (int i = 0; i < 8; ++i)
        __builtin_nontemporal_store(acc[i] + bo, po + (i << 6));
}

extern "C" void kernel_launch(void* const* d_in, const int* in_sizes, int n_in,
                              void* d_out, int out_size, void* d_ws, size_t ws_size,
                              hipStream_t stream) {
    const float* x       = (const float*)d_in[0];
    const float* weights = (const float*)d_in[1];
    const float* bias    = (const float*)d_in[2];
    const int*   conn    = (const int*)d_in[3];
    float*       out     = (float*)d_out;

    int grid = BB * C_OUT * 2;   // 8192 blocks of 256 threads
    lp_conv_bt_kernel<<<grid, 256, 0, stream>>>(x, weights, bias, conn, out);
}